// Round 11
// baseline (134.759 us; speedup 1.0000x reference)
//
#include <hip/hip_runtime.h>
#include <hip/hip_bf16.h>

// RefinementLayer2: B=2,S=384,C=4,H=128,D=768 — 3 dispatches.
// ws layout (floats):
//   0        tanh_h   (786432) = tanh(seq@{Wp,Ua}+b), z=0/1 slices (768,512)
//   786432   h_a      (393216) = seq@Ua+b         (768,512)
//   1179648  tprd_s   (393216) = C2*tanh(h_p)@W1  (3072,128) [s-major rows]
//   1572864  tref_s   (98304)  = C2*tanh(ref)@W3  (768,128)  [atomic-accum]
//   1671168  targ_s   (196608 floats as bf16)  [b][c][s][k] (coalesced for D3)

#define C2 2.885390081777927f  // 2/ln(2): exp2(C2*x) = e^(2x)

typedef __attribute__((ext_vector_type(8))) __bf16 bf16x8;
typedef __attribute__((ext_vector_type(8))) unsigned short ushort8;
typedef __attribute__((ext_vector_type(4))) float float4v;

__device__ __forceinline__ unsigned short f2bf(float f) {
  unsigned int u = __float_as_uint(f);
  u += 0x7fffu + ((u >> 16) & 1u);
  return (unsigned short)(u >> 16);
}

__device__ __forceinline__ float fast_tanh(float x) {
  float e = __builtin_amdgcn_exp2f(C2 * x);
  return 1.0f - 2.0f * __builtin_amdgcn_rcpf(1.0f + e);
}

// 64x64-tile bf16-MFMA core, BK=32, 256 threads (4 waves, 32x32 each).
__device__ __forceinline__ void gemm_core(
    const float* __restrict__ Abase, int lda,
    const float* __restrict__ Bbase, int ldb, int K,
    unsigned short* Alds, unsigned short* Blds,
    int ar, int ac, int bk, int bn,
    int wm0, int wn0, int col16, int quad, float4v acc[2][2])
{
  const float* Ap = Abase + (size_t)ar * lda + ac;
  const float* Bp = Bbase + (size_t)bk * ldb + bn;
  float4 a0 = ((const float4*)Ap)[0], a1 = ((const float4*)Ap)[1];
  float4 b0 = ((const float4*)Bp)[0], b1 = ((const float4*)Bp)[1];

  for (int k0 = 0; k0 < K; k0 += 32) {
    __syncthreads();
    {
      ushort8 o;
      o[0] = f2bf(a0.x); o[1] = f2bf(a0.y); o[2] = f2bf(a0.z); o[3] = f2bf(a0.w);
      o[4] = f2bf(a1.x); o[5] = f2bf(a1.y); o[6] = f2bf(a1.z); o[7] = f2bf(a1.w);
      *(ushort8*)&Alds[ar * 40 + ac] = o;
      float vv[8] = {b0.x, b0.y, b0.z, b0.w, b1.x, b1.y, b1.z, b1.w};
#pragma unroll
      for (int j = 0; j < 8; ++j) Blds[(bn + j) * 40 + bk] = f2bf(vv[j]);
    }
    __syncthreads();
    if (k0 + 32 < K) {
      const float4* An = (const float4*)(Ap + k0 + 32);
      const float4* Bn = (const float4*)(Bp + (size_t)(k0 + 32) * ldb);
      a0 = An[0]; a1 = An[1]; b0 = Bn[0]; b1 = Bn[1];
    }
    bf16x8 afrag[2], bfrag[2];
#pragma unroll
    for (int i = 0; i < 2; ++i)
      afrag[i] = __builtin_bit_cast(bf16x8,
          *(const ushort8*)&Alds[(wm0 + i * 16 + col16) * 40 + quad * 8]);
#pragma unroll
    for (int j = 0; j < 2; ++j)
      bfrag[j] = __builtin_bit_cast(bf16x8,
          *(const ushort8*)&Blds[(wn0 + j * 16 + col16) * 40 + quad * 8]);
#pragma unroll
    for (int i = 0; i < 2; ++i)
#pragma unroll
      for (int j = 0; j < 2; ++j)
        acc[i][j] = __builtin_amdgcn_mfma_f32_16x16x32_bf16(
            afrag[i], bfrag[j], acc[i][j], 0, 0, 0);
  }
}

// D1: z=0: tanh(seq@Wp+b); z=1: seq@Ua+b -> h_a (+tanh); z=2: zero tref.
__global__ __launch_bounds__(256) void g1_dual(
    const float* __restrict__ seq, const float* __restrict__ Wp,
    const float* __restrict__ Ua, const float* __restrict__ Wpb,
    const float* __restrict__ Uab, float* __restrict__ tanh_out,
    float* __restrict__ h_a, float* __restrict__ tref_clear)
{
  const int z = blockIdx.z;
  if (z == 2) {
    int idx = ((blockIdx.y * 8 + blockIdx.x) * 256 + threadIdx.x) * 4;
    *(float4*)&tref_clear[idx] = float4{0.f, 0.f, 0.f, 0.f};
    return;
  }
  __shared__ unsigned short Alds[64 * 40];
  __shared__ unsigned short Blds[64 * 40];
  const int tid = threadIdx.x;
  const int bn0 = blockIdx.x * 64, bm0 = blockIdx.y * 64;
  const int wid = tid >> 6, lane = tid & 63;
  const int wm0 = (wid >> 1) * 32, wn0 = (wid & 1) * 32;
  const int col16 = lane & 15, quad = lane >> 4;
  const float* B = z ? Ua : Wp;
  const float* bias = z ? Uab : Wpb;

  float4v acc[2][2];
#pragma unroll
  for (int i = 0; i < 2; ++i)
#pragma unroll
    for (int j = 0; j < 2; ++j) acc[i][j] = (float4v)(0.f);

  gemm_core(seq + (size_t)bm0 * 768, 768, B + bn0, 512, 768,
            Alds, Blds, tid >> 2, (tid & 3) * 8, tid >> 3, (tid & 7) * 8,
            wm0, wn0, col16, quad, acc);

  float* tout = tanh_out + (size_t)z * 393216;
#pragma unroll
  for (int j = 0; j < 2; ++j) {
    const int gcol = bn0 + wn0 + j * 16 + col16;
    const float bv = bias[gcol];
#pragma unroll
    for (int i = 0; i < 2; ++i)
#pragma unroll
      for (int r = 0; r < 4; ++r) {
        const int grow = bm0 + wm0 + i * 16 + quad * 4 + r;
        const float x = acc[i][j][r] + bv;
        const size_t cidx = (size_t)grow * 512 + gcol;
        tout[cidx] = fast_tanh(x);
        if (z == 1) h_a[cidx] = x;
      }
  }
}

// D2: job table, 288 blocks.
//  bid<96 : ref tile -> tanh -> tail MFMA -> atomicAdd into tref.
//  bid>=96: tanh_h{p,a}@W{1,2}; z0 -> tprd fp32 (s-major); z1 -> targ bf16 in
//           [b][c][s][k] layout (coalesced phase2 reads).
__global__ __launch_bounds__(256) void fused_mid(
    const float* __restrict__ base, const float* __restrict__ h_a,
    const float* __restrict__ tanh_h, const float* __restrict__ Wmid,
    float* __restrict__ tprd_s, unsigned short* __restrict__ targ_s,
    float* __restrict__ tref_s)
{
  __shared__ unsigned short Alds[64 * 40];
  __shared__ unsigned short Blds[64 * 40];
  __shared__ unsigned short TA[64 * 72];
  __shared__ unsigned short TB[128 * 72];

  const int tid = threadIdx.x;
  const int bid = blockIdx.x;
  const int wid = tid >> 6, lane = tid & 63;
  const int wm0 = (wid >> 1) * 32, wn0 = (wid & 1) * 32;
  const int col16 = lane & 15, quad = lane >> 4;
  const int ar = tid >> 2, ac = (tid & 3) * 8;
  const int bk = tid >> 3, bn = (tid & 7) * 8;

  float4v acc[2][2];
#pragma unroll
  for (int i = 0; i < 2; ++i)
#pragma unroll
    for (int j = 0; j < 2; ++j) acc[i][j] = (float4v)(0.f);

  if (bid < 96) {
    const int z = bid / 12, rem = bid % 12;
    const int b = z >> 2, c = z & 3;
    const int y = rem >> 1, x = rem & 1;
    const float* A = base + (size_t)b * 589824 + c * 384 + (size_t)(y * 64) * 1536;
    const float* Bm = h_a + (size_t)b * 196608 + c * 128 + x * 64;
    gemm_core(A, 1536, Bm, 512, 384, Alds, Blds, ar, ac, bk, bn,
              wm0, wn0, col16, quad, acc);

#pragma unroll
    for (int j = 0; j < 2; ++j)
#pragma unroll
      for (int i = 0; i < 2; ++i)
#pragma unroll
        for (int r = 0; r < 4; ++r)
          TA[(wm0 + i * 16 + quad * 4 + r) * 72 + wn0 + j * 16 + col16] =
              f2bf(fast_tanh(acc[i][j][r]));
    {
      const float* W3p = Wmid + 32768 + (size_t)(c * 128 + x * 64) * 128;
      const int kr = tid >> 2, nb = (tid & 3) * 32;
#pragma unroll
      for (int q = 0; q < 8; ++q) {
        float4 v = *(const float4*)(W3p + (size_t)kr * 128 + nb + q * 4);
        TB[(nb + q * 4 + 0) * 72 + kr] = f2bf(v.x);
        TB[(nb + q * 4 + 1) * 72 + kr] = f2bf(v.y);
        TB[(nb + q * 4 + 2) * 72 + kr] = f2bf(v.z);
        TB[(nb + q * 4 + 3) * 72 + kr] = f2bf(v.w);
      }
    }
    __syncthreads();

    const int mh = wid & 1, nh = wid >> 1;
    float4v acc2[2][4];
#pragma unroll
    for (int i = 0; i < 2; ++i)
#pragma unroll
      for (int j = 0; j < 4; ++j) acc2[i][j] = (float4v)(0.f);
#pragma unroll
    for (int ks = 0; ks < 2; ++ks) {
      bf16x8 af[2], bf[4];
#pragma unroll
      for (int i = 0; i < 2; ++i)
        af[i] = __builtin_bit_cast(bf16x8,
            *(const ushort8*)&TA[(mh * 32 + i * 16 + col16) * 72 + ks * 32 + quad * 8]);
#pragma unroll
      for (int j = 0; j < 4; ++j)
        bf[j] = __builtin_bit_cast(bf16x8,
            *(const ushort8*)&TB[(nh * 64 + j * 16 + col16) * 72 + ks * 32 + quad * 8]);
#pragma unroll
      for (int i = 0; i < 2; ++i)
#pragma unroll
        for (int j = 0; j < 4; ++j)
          acc2[i][j] = __builtin_amdgcn_mfma_f32_16x16x32_bf16(
              af[i], bf[j], acc2[i][j], 0, 0, 0);
    }
#pragma unroll
    for (int j = 0; j < 4; ++j) {
      const int gcol = nh * 64 + j * 16 + col16;
#pragma unroll
      for (int i = 0; i < 2; ++i)
#pragma unroll
        for (int r = 0; r < 4; ++r) {
          const int grow = b * 384 + y * 64 + mh * 32 + i * 16 + quad * 4 + r;
          atomicAdd(&tref_s[(size_t)grow * 128 + gcol], C2 * acc2[i][j][r]);
        }
    }
  } else {
    const int idx = bid - 96;
    const int x = idx & 1, y = (idx >> 1) % 48, z = idx / 96;
    const float* A = tanh_h + (size_t)z * 393216 + (size_t)(y * 64) * 128;
    const float* Bm = Wmid + z * 16384 + x * 64;
    gemm_core(A, 128, Bm, 128, 128, Alds, Blds, ar, ac, bk, bn,
              wm0, wn0, col16, quad, acc);
#pragma unroll
    for (int j = 0; j < 2; ++j) {
      const int gcol = x * 64 + wn0 + j * 16 + col16;
#pragma unroll
      for (int i = 0; i < 2; ++i)
#pragma unroll
        for (int r = 0; r < 4; ++r) {
          const int grow = y * 64 + wm0 + i * 16 + quad * 4 + r;
          const float v = C2 * acc[i][j][r];
          if (z == 0) {
            tprd_s[(size_t)grow * 128 + gcol] = v;
          } else {
            // grow is s-major row (b*384+s)*4+c; remap to [b][c][s][k].
            // grow<3072; b splits at 1536 (R10 bug: >>11 divided by 2048).
            const int bb = grow / 1536;
            const int rm = grow - bb * 1536;
            const int cc = rm & 3, s = rm >> 2;
            targ_s[(size_t)(((bb * 4 + cc) * 384) + s) * 128 + gcol] = f2bf(v);
          }
        }
    }
  }
}

// D3: out[b,p,c,a] = sum_k w_k * tanh(tprd+targ+tref+bmid).
// Grid (24,3,8): block = (pt-pair, a-tile, (b,c)); 256 thr: a=tid&127, kh=tid>>7.
// G tile (targ, [b][c][s][k] layout) staged coalescedly global->LDS once per
// block, then per-thread rows -> 32 regs. Es (exp2 per-(p,k)) in LDS per job;
// job2's Es inputs register-prefetched during job1 compute. 4-way rcp pairing.
__global__ __launch_bounds__(256) void phase2(
    const float* __restrict__ tprd, const unsigned short* __restrict__ targ,
    const float* __restrict__ tref, const float* __restrict__ bmid,
    const float* __restrict__ wout, float* __restrict__ out)
{
  __shared__ unsigned int Gs[128 * 66];  // [a][k-pair], stride 66 (8B-align rows)
  __shared__ float Es[8 * 128];
  __shared__ float Ws[128];
  __shared__ float Red[128 * 9];

  const int tid = threadIdx.x;
  const int a = tid & 127, kh = tid >> 7;
  const int p0a = blockIdx.x * 16, a0 = blockIdx.y * 128;
  const int b = blockIdx.z >> 2, c = blockIdx.z & 3;

  // ---- stage G tile: 32 KB contiguous ([b][c][a0..][k]) -> LDS, coalesced.
  // One targ row = 128 bf16 = 16 uint4 (R10 bug: base used *8).
  {
    const uint4* src = (const uint4*)targ + ((size_t)((b * 4 + c) * 384 + a0) * 16);
#pragma unroll
    for (int it = 0; it < 8; ++it) {
      const int u4 = it * 256 + tid;          // 2048 uint4s
      const int r = u4 >> 4, c4 = u4 & 15;
      uint4 v = src[u4];
      unsigned int* dst = &Gs[r * 66 + c4 * 4];
      *(uint2*)dst = uint2{v.x, v.y};
      *(uint2*)(dst + 2) = uint2{v.z, v.w};
    }
  }
  if (tid < 128) Ws[tid] = -2.f * wout[tid];
  float sw = 0.f;
  for (int k4 = 0; k4 < 32; ++k4) {
    float4 w = ((const float4*)wout)[k4];
    sw += w.x + w.y + w.z + w.w;
  }
  // prefetch Es inputs for job 1
  float tp[4], tr[4], bm[4];
#pragma unroll
  for (int it = 0; it < 4; ++it) {
    const int idx = it * 256 + tid;
    const int p = idx >> 7, k = idx & 127;
    const int row = b * 384 + p0a + p;
    tp[it] = tprd[(size_t)(row * 4 + c) * 128 + k];
    tr[it] = tref[(size_t)row * 128 + k];
    bm[it] = C2 * bmid[k];
  }
  __syncthreads();  // Gs ready

  // per-thread G row -> registers (16 x uint2; stride-66 rows, 8B aligned)
  uint2 G2[16];
  {
    const unsigned int* g = &Gs[a * 66 + kh * 32];
#pragma unroll
    for (int j2 = 0; j2 < 16; ++j2) G2[j2] = *(const uint2*)(g + j2 * 2);
  }

  const size_t ob_base = (size_t)((b * 384) * 4 + c) * 384 + a0 + a;

#pragma unroll
  for (int jj = 0; jj < 2; ++jj) {
    // store Es for this job (inputs already in regs)
#pragma unroll
    for (int it = 0; it < 4; ++it)
      Es[it * 256 + tid] = __builtin_amdgcn_exp2f(tp[it] + tr[it] + bm[it]);
    __syncthreads();  // Es ready (also guards prior Red reads)

    if (jj == 0) {  // prefetch job2's Es inputs; hidden under job1 compute
#pragma unroll
      for (int it = 0; it < 4; ++it) {
        const int idx = it * 256 + tid;
        const int p = idx >> 7, k = idx & 127;
        const int row = b * 384 + p0a + 8 + p;
        tp[it] = tprd[(size_t)(row * 4 + c) * 128 + k];
        tr[it] = tref[(size_t)row * 128 + k];
      }
    }

    float acc[8];
#pragma unroll
    for (int p = 0; p < 8; ++p) acc[p] = 0.f;

    const int kb0 = kh * 64;
#pragma unroll
    for (int j = 0; j < 8; ++j) {
      const uint2 gA = G2[2 * j], gB = G2[2 * j + 1];
      const float eg0 = __builtin_amdgcn_exp2f(__uint_as_float(gA.x << 16));
      const float eg1 = __builtin_amdgcn_exp2f(__uint_as_float(gA.x & 0xffff0000u));
      const float eg2 = __builtin_amdgcn_exp2f(__uint_as_float(gA.y << 16));
      const float eg3 = __builtin_amdgcn_exp2f(__uint_as_float(gA.y & 0xffff0000u));
      const float eg4 = __builtin_amdgcn_exp2f(__uint_as_float(gB.x << 16));
      const float eg5 = __builtin_amdgcn_exp2f(__uint_as_float(gB.x & 0xffff0000u));
      const float eg6 = __builtin_amdgcn_exp2f(__uint_as_float(gB.y << 16));
      const float eg7 = __builtin_amdgcn_exp2f(__uint_as_float(gB.y & 0xffff0000u));
      const int kb = kb0 + j * 8;
      const float4 wqA = *(const float4*)&Ws[kb];
      const float4 wqB = *(const float4*)&Ws[kb + 4];
#pragma unroll
      for (int p = 0; p < 8; ++p) {
        const float4 efA = *(const float4*)&Es[p * 128 + kb];
        const float4 efB = *(const float4*)&Es[p * 128 + kb + 4];
        float d0 = fmaf(efA.x, eg0, 1.f);
        float d1 = fmaf(efA.y, eg1, 1.f);
        float d2 = fmaf(efA.z, eg2, 1.f);
        float d3 = fmaf(efA.w, eg3, 1.f);
        float d01 = d0 * d1, d23 = d2 * d3;
        float n01 = fmaf(wqA.y, d0, wqA.x * d1);
        float n23 = fmaf(wqA.w, d2, wqA.z * d3);
        float num = fmaf(n01, d23, n23 * d01);
        acc[p] = fmaf(num, __builtin_amdgcn_rcpf(d01 * d23), acc[p]);
        d0 = fmaf(efB.x, eg4, 1.f);
        d1 = fmaf(efB.y, eg5, 1.f);
        d2 = fmaf(efB.z, eg6, 1.f);
        d3 = fmaf(efB.w, eg7, 1.f);
        d01 = d0 * d1; d23 = d2 * d3;
        n01 = fmaf(wqB.y, d0, wqB.x * d1);
        n23 = fmaf(wqB.w, d2, wqB.z * d3);
        num = fmaf(n01, d23, n23 * d01);
        acc[p] = fmaf(num, __builtin_amdgcn_rcpf(d01 * d23), acc[p]);
      }
    }

    if (kh) {
#pragma unroll
      for (int p = 0; p < 8; ++p) Red[a * 9 + p] = acc[p];
    }
    __syncthreads();  // Red ready; Es reads of this job done
    if (!kh) {
      const size_t ob = ob_base + (size_t)(p0a + jj * 8) * 1536;
#pragma unroll
      for (int p = 0; p < 8; ++p)
        out[ob + (size_t)p * 1536] = sw + acc[p] + Red[a * 9 + p];
    }
  }
}

extern "C" void kernel_launch(void* const* d_in, const int* in_sizes, int n_in,
                              void* d_out, int out_size, void* d_ws, size_t ws_size,
                              hipStream_t stream) {
  (void)in_sizes; (void)n_in; (void)out_size; (void)ws_size;
  const float* seq  = (const float*)d_in[0];
  const float* base = (const float*)d_in[1];
  const float* Wp   = (const float*)d_in[2];
  const float* Wpb  = (const float*)d_in[3];
  const float* Ua   = (const float*)d_in[4];
  const float* Uab  = (const float*)d_in[5];
  const float* Wmid = (const float*)d_in[6];
  const float* bmid = (const float*)d_in[7];
  const float* wout = (const float*)d_in[8];
  float* out = (float*)d_out;

  float* ws = (float*)d_ws;
  float* tanh_h = ws;                     // (768,512) x2 (z=0 hp, z=1 ha)
  float* h_a    = ws + 786432;            // (768,512)
  float* tprd_s = ws + 1179648;           // (3072,128) *C2, s-major
  float* tref_s = ws + 1572864;           // (768,128)  *C2, atomic
  unsigned short* targ_s = (unsigned short*)(ws + 1671168);  // [b][c][s][k] bf16

  g1_dual<<<dim3(8, 12, 3), dim3(256), 0, stream>>>(
      seq, Wp, Ua, Wpb, Uab, tanh_h, h_a, tref_s);
  fused_mid<<<dim3(288), dim3(256), 0, stream>>>(
      base, h_a, tanh_h, Wmid, tprd_s, targ_s, tref_s);
  phase2<<<dim3(24, 3, 8), dim3(256), 0, stream>>>(
      tprd_s, targ_s, tref_s, bmid, wout, out);
}

// Round 13
// 133.661 us; speedup vs baseline: 1.0082x; 1.0082x over previous
//
#include <hip/hip_runtime.h>
#include <hip/hip_bf16.h>

// RefinementLayer2: B=2,S=384,C=4,H=128,D=768 — 3 dispatches.
// ws layout (floats):
//   0        tanh_h   (786432) = tanh(seq@{Wp,Ua}+b), z=0/1 slices (768,512)
//   786432   h_a      (393216) = seq@Ua+b         (768,512)
//   1179648  tprd_s   (393216) = C2*tanh(h_p)@W1  (3072,128) [s-major rows]
//   1572864  tref_s   (98304)  = C2*tanh(ref)@W3  (768,128)  [atomic-accum]
//   1671168  targ_s   (196608 floats as bf16) [b][c][k2][s] uint k-pairs:
//            uint at ((b*4+c)*64 + k2)*384 + s  — phase2 loads are coalesced.

#define C2 2.885390081777927f  // 2/ln(2): exp2(C2*x) = e^(2x)

typedef __attribute__((ext_vector_type(8))) __bf16 bf16x8;
typedef __attribute__((ext_vector_type(8))) unsigned short ushort8;
typedef __attribute__((ext_vector_type(4))) float float4v;

__device__ __forceinline__ unsigned short f2bf(float f) {
  unsigned int u = __float_as_uint(f);
  u += 0x7fffu + ((u >> 16) & 1u);
  return (unsigned short)(u >> 16);
}

__device__ __forceinline__ float fast_tanh(float x) {
  float e = __builtin_amdgcn_exp2f(C2 * x);
  return 1.0f - 2.0f * __builtin_amdgcn_rcpf(1.0f + e);
}

// 64x64-tile bf16-MFMA core, BK=32, 256 threads (4 waves, 32x32 each).
__device__ __forceinline__ void gemm_core(
    const float* __restrict__ Abase, int lda,
    const float* __restrict__ Bbase, int ldb, int K,
    unsigned short* Alds, unsigned short* Blds,
    int ar, int ac, int bk, int bn,
    int wm0, int wn0, int col16, int quad, float4v acc[2][2])
{
  const float* Ap = Abase + (size_t)ar * lda + ac;
  const float* Bp = Bbase + (size_t)bk * ldb + bn;
  float4 a0 = ((const float4*)Ap)[0], a1 = ((const float4*)Ap)[1];
  float4 b0 = ((const float4*)Bp)[0], b1 = ((const float4*)Bp)[1];

  for (int k0 = 0; k0 < K; k0 += 32) {
    __syncthreads();
    {
      ushort8 o;
      o[0] = f2bf(a0.x); o[1] = f2bf(a0.y); o[2] = f2bf(a0.z); o[3] = f2bf(a0.w);
      o[4] = f2bf(a1.x); o[5] = f2bf(a1.y); o[6] = f2bf(a1.z); o[7] = f2bf(a1.w);
      *(ushort8*)&Alds[ar * 40 + ac] = o;
      float vv[8] = {b0.x, b0.y, b0.z, b0.w, b1.x, b1.y, b1.z, b1.w};
#pragma unroll
      for (int j = 0; j < 8; ++j) Blds[(bn + j) * 40 + bk] = f2bf(vv[j]);
    }
    __syncthreads();
    if (k0 + 32 < K) {
      const float4* An = (const float4*)(Ap + k0 + 32);
      const float4* Bn = (const float4*)(Bp + (size_t)(k0 + 32) * ldb);
      a0 = An[0]; a1 = An[1]; b0 = Bn[0]; b1 = Bn[1];
    }
    bf16x8 afrag[2], bfrag[2];
#pragma unroll
    for (int i = 0; i < 2; ++i)
      afrag[i] = __builtin_bit_cast(bf16x8,
          *(const ushort8*)&Alds[(wm0 + i * 16 + col16) * 40 + quad * 8]);
#pragma unroll
    for (int j = 0; j < 2; ++j)
      bfrag[j] = __builtin_bit_cast(bf16x8,
          *(const ushort8*)&Blds[(wn0 + j * 16 + col16) * 40 + quad * 8]);
#pragma unroll
    for (int i = 0; i < 2; ++i)
#pragma unroll
      for (int j = 0; j < 2; ++j)
        acc[i][j] = __builtin_amdgcn_mfma_f32_16x16x32_bf16(
            afrag[i], bfrag[j], acc[i][j], 0, 0, 0);
  }
}

// D1: z=0: tanh(seq@Wp+b); z=1: seq@Ua+b -> h_a (+tanh); z=2: zero tref.
__global__ __launch_bounds__(256) void g1_dual(
    const float* __restrict__ seq, const float* __restrict__ Wp,
    const float* __restrict__ Ua, const float* __restrict__ Wpb,
    const float* __restrict__ Uab, float* __restrict__ tanh_out,
    float* __restrict__ h_a, float* __restrict__ tref_clear)
{
  const int z = blockIdx.z;
  if (z == 2) {
    int idx = ((blockIdx.y * 8 + blockIdx.x) * 256 + threadIdx.x) * 4;
    *(float4*)&tref_clear[idx] = float4{0.f, 0.f, 0.f, 0.f};
    return;
  }
  __shared__ unsigned short Alds[64 * 40];
  __shared__ unsigned short Blds[64 * 40];
  const int tid = threadIdx.x;
  const int bn0 = blockIdx.x * 64, bm0 = blockIdx.y * 64;
  const int wid = tid >> 6, lane = tid & 63;
  const int wm0 = (wid >> 1) * 32, wn0 = (wid & 1) * 32;
  const int col16 = lane & 15, quad = lane >> 4;
  const float* B = z ? Ua : Wp;
  const float* bias = z ? Uab : Wpb;

  float4v acc[2][2];
#pragma unroll
  for (int i = 0; i < 2; ++i)
#pragma unroll
    for (int j = 0; j < 2; ++j) acc[i][j] = (float4v)(0.f);

  gemm_core(seq + (size_t)bm0 * 768, 768, B + bn0, 512, 768,
            Alds, Blds, tid >> 2, (tid & 3) * 8, tid >> 3, (tid & 7) * 8,
            wm0, wn0, col16, quad, acc);

  float* tout = tanh_out + (size_t)z * 393216;
#pragma unroll
  for (int j = 0; j < 2; ++j) {
    const int gcol = bn0 + wn0 + j * 16 + col16;
    const float bv = bias[gcol];
#pragma unroll
    for (int i = 0; i < 2; ++i)
#pragma unroll
      for (int r = 0; r < 4; ++r) {
        const int grow = bm0 + wm0 + i * 16 + quad * 4 + r;
        const float x = acc[i][j][r] + bv;
        const size_t cidx = (size_t)grow * 512 + gcol;
        tout[cidx] = fast_tanh(x);
        if (z == 1) h_a[cidx] = x;
      }
  }
}

// D2: job table, 288 blocks.
//  bid<96 : ref tile -> tanh -> tail MFMA -> atomicAdd into tref.
//  bid>=96: tanh_h{p,a}@W{1,2}; z0 -> tprd fp32 (s-major); z1 -> targ bf16 in
//           [b][c][k2][s] layout via LDS transpose (coalesced phase2 reads).
__global__ __launch_bounds__(256) void fused_mid(
    const float* __restrict__ base, const float* __restrict__ h_a,
    const float* __restrict__ tanh_h, const float* __restrict__ Wmid,
    float* __restrict__ tprd_s, unsigned int* __restrict__ targ_u,
    float* __restrict__ tref_s)
{
  __shared__ __align__(16) unsigned char smem[37888];
  unsigned short* Alds = (unsigned short*)smem;            // 5120 B
  unsigned short* Blds = (unsigned short*)(smem + 5120);   // 5120 B
  unsigned short* TA   = (unsigned short*)(smem + 10240);  // 9216 B (bid<96)
  unsigned short* TB   = (unsigned short*)(smem + 19456);  // 18432 B (bid<96)

  const int tid = threadIdx.x;
  const int bid = blockIdx.x;
  const int wid = tid >> 6, lane = tid & 63;
  const int wm0 = (wid >> 1) * 32, wn0 = (wid & 1) * 32;
  const int col16 = lane & 15, quad = lane >> 4;
  const int ar = tid >> 2, ac = (tid & 3) * 8;
  const int bk = tid >> 3, bn = (tid & 7) * 8;

  float4v acc[2][2];
#pragma unroll
  for (int i = 0; i < 2; ++i)
#pragma unroll
    for (int j = 0; j < 2; ++j) acc[i][j] = (float4v)(0.f);

  if (bid < 96) {
    const int z = bid / 12, rem = bid % 12;
    const int b = z >> 2, c = z & 3;
    const int y = rem >> 1, x = rem & 1;
    const float* A = base + (size_t)b * 589824 + c * 384 + (size_t)(y * 64) * 1536;
    const float* Bm = h_a + (size_t)b * 196608 + c * 128 + x * 64;
    gemm_core(A, 1536, Bm, 512, 384, Alds, Blds, ar, ac, bk, bn,
              wm0, wn0, col16, quad, acc);

#pragma unroll
    for (int j = 0; j < 2; ++j)
#pragma unroll
      for (int i = 0; i < 2; ++i)
#pragma unroll
        for (int r = 0; r < 4; ++r)
          TA[(wm0 + i * 16 + quad * 4 + r) * 72 + wn0 + j * 16 + col16] =
              f2bf(fast_tanh(acc[i][j][r]));
    {
      const float* W3p = Wmid + 32768 + (size_t)(c * 128 + x * 64) * 128;
      const int kr = tid >> 2, nb = (tid & 3) * 32;
#pragma unroll
      for (int q = 0; q < 8; ++q) {
        float4 v = *(const float4*)(W3p + (size_t)kr * 128 + nb + q * 4);
        TB[(nb + q * 4 + 0) * 72 + kr] = f2bf(v.x);
        TB[(nb + q * 4 + 1) * 72 + kr] = f2bf(v.y);
        TB[(nb + q * 4 + 2) * 72 + kr] = f2bf(v.z);
        TB[(nb + q * 4 + 3) * 72 + kr] = f2bf(v.w);
      }
    }
    __syncthreads();

    const int mh = wid & 1, nh = wid >> 1;
    float4v acc2[2][4];
#pragma unroll
    for (int i = 0; i < 2; ++i)
#pragma unroll
      for (int j = 0; j < 4; ++j) acc2[i][j] = (float4v)(0.f);
#pragma unroll
    for (int ks = 0; ks < 2; ++ks) {
      bf16x8 af[2], bf[4];
#pragma unroll
      for (int i = 0; i < 2; ++i)
        af[i] = __builtin_bit_cast(bf16x8,
            *(const ushort8*)&TA[(mh * 32 + i * 16 + col16) * 72 + ks * 32 + quad * 8]);
#pragma unroll
      for (int j = 0; j < 4; ++j)
        bf[j] = __builtin_bit_cast(bf16x8,
            *(const ushort8*)&TB[(nh * 64 + j * 16 + col16) * 72 + ks * 32 + quad * 8]);
#pragma unroll
      for (int i = 0; i < 2; ++i)
#pragma unroll
        for (int j = 0; j < 4; ++j)
          acc2[i][j] = __builtin_amdgcn_mfma_f32_16x16x32_bf16(
              af[i], bf[j], acc2[i][j], 0, 0, 0);
    }
#pragma unroll
    for (int j = 0; j < 4; ++j) {
      const int gcol = nh * 64 + j * 16 + col16;
#pragma unroll
      for (int i = 0; i < 2; ++i)
#pragma unroll
        for (int r = 0; r < 4; ++r) {
          const int grow = b * 384 + y * 64 + mh * 32 + i * 16 + quad * 4 + r;
          atomicAdd(&tref_s[(size_t)grow * 128 + gcol], C2 * acc2[i][j][r]);
        }
    }
  } else {
    const int idx = bid - 96;
    const int x = idx & 1, y = (idx >> 1) % 48, z = idx / 96;
    const float* A = tanh_h + (size_t)z * 393216 + (size_t)(y * 64) * 128;
    const float* Bm = Wmid + z * 16384 + x * 64;
    gemm_core(A, 128, Bm, 128, 128, Alds, Blds, ar, ac, bk, bn,
              wm0, wn0, col16, quad, acc);
    if (z == 0) {
#pragma unroll
      for (int j = 0; j < 2; ++j) {
        const int gcol = x * 64 + wn0 + j * 16 + col16;
#pragma unroll
        for (int i = 0; i < 2; ++i)
#pragma unroll
          for (int r = 0; r < 4; ++r) {
            const int grow = y * 64 + wm0 + i * 16 + quad * 4 + r;
            tprd_s[(size_t)grow * 128 + gcol] = C2 * acc[i][j][r];
          }
      }
    } else {
      // Transpose 64 rows (16 s x 4 c, b=y/24, s0=(y%24)*16) x 64 k (x*64..)
      // into [c][k2(32)][s(16)] uints via LDS, then coalesced write-out.
      unsigned short* Tu = (unsigned short*)(smem + 10240);  // [4*32][17] uints
#pragma unroll
      for (int j = 0; j < 2; ++j) {
        const int gcol = x * 64 + wn0 + j * 16 + col16;
        const int k2l = ((wn0 + j * 16 + col16) >> 1), half = gcol & 1;
#pragma unroll
        for (int i = 0; i < 2; ++i)
#pragma unroll
          for (int r = 0; r < 4; ++r) {
            const int local = wm0 + i * 16 + quad * 4 + r;  // row in tile
            const int cc = local & 3, sl = local >> 2;
            Tu[(((cc * 32 + k2l) * 17) + sl) * 2 + half] =
                f2bf(C2 * acc[i][j][r]);
          }
      }
      __syncthreads();
      const unsigned int* T = (const unsigned int*)Tu;
      const int b = y / 24, s0 = (y % 24) * 16;
#pragma unroll
      for (int it = 0; it < 8; ++it) {
        const int idx2 = it * 256 + tid;        // 2048 uints
        const int cc = idx2 >> 9, k2l = (idx2 >> 4) & 31, sl = idx2 & 15;
        targ_u[(size_t)((b * 4 + cc) * 64 + x * 32 + k2l) * 384 + s0 + sl] =
            T[(cc * 32 + k2l) * 17 + sl];
      }
    }
  }
}

// D3: out[b,p,c,a] = sum_k w_k * tanh(tprd+targ+tref+bmid).
// Grid (48,3,8), 128 threads (thread <-> a). G row loaded DIRECTLY from
// global in [b][c][k2][s] layout: 64 coalesced dword loads (lane = s),
// issued up-front. LDS only Es (4KB) + Ws. j loop covers ALL 16 k-octets
// (R12 bug: ran 8 of 16 -> half the k-sum missing).
__global__ __launch_bounds__(128) void phase2(
    const float* __restrict__ tprd, const unsigned int* __restrict__ targ_u,
    const float* __restrict__ tref, const float* __restrict__ bmid,
    const float* __restrict__ wout, float* __restrict__ out)
{
  __shared__ float Es[8 * 128];
  __shared__ float Ws[128];

  const int tid = threadIdx.x;
  const int p0 = blockIdx.x * 8, a0 = blockIdx.y * 128;
  const int b = blockIdx.z >> 2, c = blockIdx.z & 3;

  // G: this thread's 128 k (64 uint k-pairs), coalesced (lane = s).
  unsigned int G[64];
  {
    const unsigned int* gp = targ_u + (size_t)((b * 4 + c) * 64) * 384 + a0 + tid;
#pragma unroll
    for (int j2 = 0; j2 < 64; ++j2) G[j2] = gp[(size_t)j2 * 384];
  }

  Ws[tid] = -2.f * wout[tid];
#pragma unroll
  for (int it = 0; it < 8; ++it) {  // Es[8][128]
    const int idx = it * 128 + tid;
    const int p = idx >> 7, k = idx & 127;
    const int row = b * 384 + p0 + p;
    Es[idx] = __builtin_amdgcn_exp2f(
        tprd[(size_t)(row * 4 + c) * 128 + k] +
        tref[(size_t)row * 128 + k] + C2 * bmid[k]);
  }
  float sw = 0.f;
  for (int k4 = 0; k4 < 32; ++k4) {
    float4 w = ((const float4*)wout)[k4];
    sw += w.x + w.y + w.z + w.w;
  }
  __syncthreads();

  float acc[8];
#pragma unroll
  for (int p = 0; p < 8; ++p) acc[p] = 0.f;

#pragma unroll
  for (int j = 0; j < 16; ++j) {  // 8 k per j from registers; 16*8 = 128 k
    const unsigned int g0 = G[4 * j], g1 = G[4 * j + 1];
    const unsigned int g2 = G[4 * j + 2], g3 = G[4 * j + 3];
    const float eg0 = __builtin_amdgcn_exp2f(__uint_as_float(g0 << 16));
    const float eg1 = __builtin_amdgcn_exp2f(__uint_as_float(g0 & 0xffff0000u));
    const float eg2 = __builtin_amdgcn_exp2f(__uint_as_float(g1 << 16));
    const float eg3 = __builtin_amdgcn_exp2f(__uint_as_float(g1 & 0xffff0000u));
    const float eg4 = __builtin_amdgcn_exp2f(__uint_as_float(g2 << 16));
    const float eg5 = __builtin_amdgcn_exp2f(__uint_as_float(g2 & 0xffff0000u));
    const float eg6 = __builtin_amdgcn_exp2f(__uint_as_float(g3 << 16));
    const float eg7 = __builtin_amdgcn_exp2f(__uint_as_float(g3 & 0xffff0000u));
    const int kb = j * 8;
    const float4 wqA = *(const float4*)&Ws[kb];
    const float4 wqB = *(const float4*)&Ws[kb + 4];
#pragma unroll
    for (int p = 0; p < 8; ++p) {
      const float4 efA = *(const float4*)&Es[p * 128 + kb];
      const float4 efB = *(const float4*)&Es[p * 128 + kb + 4];
      float d0 = fmaf(efA.x, eg0, 1.f);
      float d1 = fmaf(efA.y, eg1, 1.f);
      float d2 = fmaf(efA.z, eg2, 1.f);
      float d3 = fmaf(efA.w, eg3, 1.f);
      float d01 = d0 * d1, d23 = d2 * d3;
      float n01 = fmaf(wqA.y, d0, wqA.x * d1);
      float n23 = fmaf(wqA.w, d2, wqA.z * d3);
      float num = fmaf(n01, d23, n23 * d01);
      acc[p] = fmaf(num, __builtin_amdgcn_rcpf(d01 * d23), acc[p]);
      d0 = fmaf(efB.x, eg4, 1.f);
      d1 = fmaf(efB.y, eg5, 1.f);
      d2 = fmaf(efB.z, eg6, 1.f);
      d3 = fmaf(efB.w, eg7, 1.f);
      d01 = d0 * d1; d23 = d2 * d3;
      n01 = fmaf(wqB.y, d0, wqB.x * d1);
      n23 = fmaf(wqB.w, d2, wqB.z * d3);
      num = fmaf(n01, d23, n23 * d01);
      acc[p] = fmaf(num, __builtin_amdgcn_rcpf(d01 * d23), acc[p]);
    }
  }

  const size_t ob = (size_t)((b * 384 + p0) * 4 + c) * 384 + a0 + tid;
#pragma unroll
  for (int p = 0; p < 8; ++p)
    out[ob + (size_t)p * 1536] = sw + acc[p];
}

extern "C" void kernel_launch(void* const* d_in, const int* in_sizes, int n_in,
                              void* d_out, int out_size, void* d_ws, size_t ws_size,
                              hipStream_t stream) {
  (void)in_sizes; (void)n_in; (void)out_size; (void)ws_size;
  const float* seq  = (const float*)d_in[0];
  const float* base = (const float*)d_in[1];
  const float* Wp   = (const float*)d_in[2];
  const float* Wpb  = (const float*)d_in[3];
  const float* Ua   = (const float*)d_in[4];
  const float* Uab  = (const float*)d_in[5];
  const float* Wmid = (const float*)d_in[6];
  const float* bmid = (const float*)d_in[7];
  const float* wout = (const float*)d_in[8];
  float* out = (float*)d_out;

  float* ws = (float*)d_ws;
  float* tanh_h = ws;                     // (768,512) x2 (z=0 hp, z=1 ha)
  float* h_a    = ws + 786432;            // (768,512)
  float* tprd_s = ws + 1179648;           // (3072,128) *C2, s-major
  float* tref_s = ws + 1572864;           // (768,128)  *C2, atomic
  unsigned int* targ_u = (unsigned int*)(ws + 1671168);  // [b][c][k2][s] uints

  g1_dual<<<dim3(8, 12, 3), dim3(256), 0, stream>>>(
      seq, Wp, Ua, Wpb, Uab, tanh_h, h_a, tref_s);
  fused_mid<<<dim3(288), dim3(256), 0, stream>>>(
      base, h_a, tanh_h, Wmid, tprd_s, targ_u, tref_s);
  phase2<<<dim3(48, 3, 8), dim3(128), 0, stream>>>(
      tprd_s, targ_u, tref_s, bmid, wout, out);
}